// Round 14
// baseline (47.533 us; speedup 1.0000x reference)
//
#include <hip/hip_runtime.h>
#include <cmath>

namespace {
constexpr int G8   = 8;
constexpr int O8   = 8;
constexpr int I8   = 8;
constexpr int KS   = 7;
constexpr int S49  = KS * KS;        // 49
constexpr int CIN  = 128;
constexpr int COUT = 128;
constexpr int SLICE = G8 * S49;      // 392 floats per (co,ci)
constexpr int CI_PER_BLK = 4;        // ci packed into float4 LDS lanes
constexpr int NT = 448;              // threads 0..391 map to (i,s)
constexpr int RUN = CI_PER_BLK * SLICE; // 1568 floats: contiguous output per (co,o) chunk
typedef float vfloat4 __attribute__((ext_vector_type(4)));  // native vec for nontemporal builtins
}

__global__ __launch_bounds__(NT) void expand_kernel(
    const float* __restrict__ weight,   // [COUT, CIN, G, 7, 7]
    const float* __restrict__ in_H,     // [8]
    const float* __restrict__ out_H,    // [8]
    const float* __restrict__ grid_Rn,  // [7,7,2]
    const float* __restrict__ mask,     // [7,7]
    float* __restrict__ out)            // [COUT, O, CIN, I, 7, 7]
{
    __shared__ float4 Wl[SLICE];        // [g*49+p] -> {ci0..ci0+3}
    __shared__ float4 wtab[O8 * S49];   // per-(o,s) bilinear weights * mask
    __shared__ unsigned int ttab[O8 * S49]; // per-(o,s) packed tap indices
    __shared__ unsigned int hg[O8 * I8];
    __shared__ float hw[O8 * I8];
    __shared__ __align__(16) float stag[2][RUN]; // double-buffered store staging

    const int tid = threadIdx.x;
    const int bx  = blockIdx.x;
    const int co  = bx >> 5;                 // 32 blocks per co (128 ci / 4)
    const int ci0 = (bx & 31) * CI_PER_BLK;

    // ---- weight staging: transpose 4 ci-slices into float4-interleaved LDS ----
    if (tid < SLICE) {
        const float* b0 = weight + (size_t)(co * CIN + ci0) * SLICE + tid;
        float4 v;                            // read-once: bypass L2 allocation
        v.x = __builtin_nontemporal_load(b0);
        v.y = __builtin_nontemporal_load(b0 + SLICE);
        v.z = __builtin_nontemporal_load(b0 + 2 * SLICE);
        v.w = __builtin_nontemporal_load(b0 + 3 * SLICE);
        Wl[tid] = v;

        // ---- geometry tables: one thread per (o,s) combo ----
        const int o = tid / S49;
        const int s = tid - o * S49;
        const float gx = grid_Rn[2 * s];
        const float gy = grid_Rn[2 * s + 1];
        const float mv = mask[s];
        const float a  = -out_H[o];          // out_inv, same as reference
        const float c  = cosf(a);
        const float sn = sinf(a);
        const float rx = c * gx - sn * gy;   // left_apply_to_Rn
        const float ry = sn * gx + c * gy;
        const float px = (rx + 1.0f) * 0.5f * (float)(KS - 1);
        const float py = (ry + 1.0f) * 0.5f * (float)(KS - 1);
        const float fx0 = floorf(px), fy0 = floorf(py);
        const float wx = px - fx0, wy = py - fy0;
        const int x0 = (int)fx0, y0 = (int)fy0;
        const int x1 = x0 + 1,   y1 = y0 + 1;
        const int xc0 = min(max(x0, 0), KS - 1);
        const int xc1 = min(max(x1, 0), KS - 1);
        const int yc0 = min(max(y0, 0), KS - 1);
        const int yc1 = min(max(y1, 0), KS - 1);
        const bool ix0 = (x0 >= 0) && (x0 <= KS - 1);
        const bool ix1 = (x1 >= 0) && (x1 <= KS - 1);
        const bool iy0 = (y0 >= 0) && (y0 <= KS - 1);
        const bool iy1 = (y1 >= 0) && (y1 <= KS - 1);
        float w00 = (1.0f - wx) * (1.0f - wy); w00 = (ix0 && iy0) ? w00 : 0.0f;
        float w10 = wx * (1.0f - wy);          w10 = (ix1 && iy0) ? w10 : 0.0f;
        float w01 = (1.0f - wx) * wy;          w01 = (ix0 && iy1) ? w01 : 0.0f;
        float w11 = wx * wy;                   w11 = (ix1 && iy1) ? w11 : 0.0f;
        float4 wv;                            // premultiplied by mask (bf16-absorbed reassoc)
        wv.x = w00 * mv; wv.y = w10 * mv; wv.z = w01 * mv; wv.w = w11 * mv;
        wtab[tid] = wv;
        const unsigned t00 = (unsigned)(yc0 * KS + xc0);
        const unsigned t10 = (unsigned)(yc0 * KS + xc1);
        const unsigned t01 = (unsigned)(yc1 * KS + xc0);
        const unsigned t11 = (unsigned)(yc1 * KS + xc1);
        ttab[tid] = t00 | (t10 << 8) | (t01 << 16) | (t11 << 24);
    }
    if (tid < O8 * I8) {                     // threads 0..63: H-interp table
        const int o = tid >> 3, i = tid & 7;
        const float TP   = 6.28318530717958647692f;   // float32(2*pi)
        const float STEP = 0.78539816339744830961f;   // float32(2*pi/8)
        float q = -out_H[o] + in_H[i];
        float m = fmodf(q, TP);
        if (m < 0.0f) m += TP;               // jnp.mod semantics
        const float pos = m / STEP;
        const float b = floorf(pos);
        const int i0 = ((int)b) & 7;         // b in [0,8], 8&7==0 matches %8
        const int i1 = (i0 + 1) & 7;
        hg[tid] = (unsigned)(i0 * S49) | ((unsigned)(i1 * S49) << 16);
        hw[tid] = pos - b;
    }
    __syncthreads();

    // active threads: tid 0..391 (wave 6 partially active; all 7 waves reach barriers)
    const bool active = (tid < SLICE);
    const int i  = active ? (tid / S49) : 0;          // 0..7
    const int s  = active ? (tid - i * S49) : 0;      // 0..48
    const int sci = tid / (SLICE / CI_PER_BLK);       // store-phase ci (tid/98), 0..3
    const int se4 = tid - sci * (SLICE / CI_PER_BLK); // store-phase float4 idx, 0..97

    // contiguous 1568-float output chunk per (co,o): [co][o][ci0..ci0+3][392]
    size_t ochunk = ((size_t)(co * O8) * CIN + ci0) * SLICE;

    #pragma unroll
    for (int o = 0; o < O8; ++o) {
        float* sb = stag[o & 1];
        if (active) {
            const float4 wv = wtab[o * S49 + s];
            const unsigned tp = ttab[o * S49 + s];
            const int t00 = (int)(tp & 0xffu);
            const int t10 = (int)((tp >> 8) & 0xffu);
            const int t01 = (int)((tp >> 16) & 0xffu);
            const int t11 = (int)(tp >> 24);

            const unsigned hp = hg[(o << 3) + i];
            const float    wh = hw[(o << 3) + i];
            const int g0 = (int)(hp & 0xffffu);
            const int g1 = (int)(hp >> 16);

            float ax, ay, az, aw;
            const bool lo = (wh <= 1e-4f);
            const bool hi = (wh >= 1.0f - 1e-4f);
            if (lo || hi) {
                // degenerate H-blend: single slice; dropped term <= 1e-4*|W| ~ 5e-7
                const int   g  = lo ? g0 : g1;
                const float sc = lo ? (1.0f - wh) : wh;
                const float4 v00 = Wl[g + t00];
                const float4 v10 = Wl[g + t10];
                const float4 v01 = Wl[g + t01];
                const float4 v11 = Wl[g + t11];
                ax = sc * (wv.x * v00.x + wv.y * v10.x + wv.z * v01.x + wv.w * v11.x);
                ay = sc * (wv.x * v00.y + wv.y * v10.y + wv.z * v01.y + wv.w * v11.y);
                az = sc * (wv.x * v00.z + wv.y * v10.z + wv.z * v01.z + wv.w * v11.z);
                aw = sc * (wv.x * v00.w + wv.y * v10.w + wv.z * v01.w + wv.w * v11.w);
            } else {
                const float4 u00 = Wl[g0 + t00];
                const float4 u10 = Wl[g0 + t10];
                const float4 u01 = Wl[g0 + t01];
                const float4 u11 = Wl[g0 + t11];
                const float4 v00 = Wl[g1 + t00];
                const float4 v10 = Wl[g1 + t10];
                const float4 v01 = Wl[g1 + t01];
                const float4 v11 = Wl[g1 + t11];
                const float wA = (1.0f - wh), wB = wh;
                ax = wA * (wv.x * u00.x + wv.y * u10.x + wv.z * u01.x + wv.w * u11.x)
                   + wB * (wv.x * v00.x + wv.y * v10.x + wv.z * v01.x + wv.w * v11.x);
                ay = wA * (wv.x * u00.y + wv.y * u10.y + wv.z * u01.y + wv.w * u11.y)
                   + wB * (wv.x * v00.y + wv.y * v10.y + wv.z * v01.y + wv.w * v11.y);
                az = wA * (wv.x * u00.z + wv.y * u10.z + wv.z * u01.z + wv.w * u11.z)
                   + wB * (wv.x * v00.z + wv.y * v10.z + wv.z * v01.z + wv.w * v11.z);
                aw = wA * (wv.x * u00.w + wv.y * u10.w + wv.z * u01.w + wv.w * u11.w)
                   + wB * (wv.x * v00.w + wv.y * v10.w + wv.z * v01.w + wv.w * v11.w);
            }
            // stage results: [ci][e] layout inside the 1568-float chunk
            sb[            tid] = ax;
            sb[    SLICE + tid] = ay;
            sb[2 * SLICE + tid] = az;
            sb[3 * SLICE + tid] = aw;
        }
        __syncthreads();   // staging visible; also orders o+2 writes after o reads
        if (active) {
            const vfloat4 sv = *reinterpret_cast<const vfloat4*>(&sb[sci * SLICE + 4 * se4]);
            vfloat4* dst = reinterpret_cast<vfloat4*>(out + ochunk + sci * SLICE + 4 * se4);
            __builtin_nontemporal_store(sv, dst);   // streaming store: skip L2 allocate
        }
        ochunk += (size_t)CIN * SLICE;       // advance o by 128*392
    }
}

extern "C" void kernel_launch(void* const* d_in, const int* in_sizes, int n_in,
                              void* d_out, int out_size, void* d_ws, size_t ws_size,
                              hipStream_t stream) {
    const float* weight  = (const float*)d_in[0];
    const float* in_H    = (const float*)d_in[1];
    const float* out_H   = (const float*)d_in[2];
    /* d_in[3] = grid_H (unused) */
    const float* grid_Rn = (const float*)d_in[4];
    const float* mask    = (const float*)d_in[5];
    float* outp = (float*)d_out;

    const int nblocks = COUT * (CIN / CI_PER_BLK);  // 4096
    hipLaunchKernelGGL(expand_kernel, dim3(nblocks), dim3(NT), 0, stream,
                       weight, in_H, out_H, grid_Rn, mask, outp);
}

// Round 15
// 40.720 us; speedup vs baseline: 1.1673x; 1.1673x over previous
//
#include <hip/hip_runtime.h>
#include <cmath>

namespace {
constexpr int G8   = 8;
constexpr int O8   = 8;
constexpr int I8   = 8;
constexpr int KS   = 7;
constexpr int S49  = KS * KS;        // 49
constexpr int CIN  = 128;
constexpr int COUT = 128;
constexpr int SLICE = G8 * S49;      // 392 floats per (co,ci)
constexpr int CI_PER_BLK = 4;        // ci packed into float4 LDS lanes
constexpr int NT = 448;              // threads 0..391 map to (i,s)
constexpr int RUN = CI_PER_BLK * SLICE; // 1568 floats: contiguous output per (co,o) chunk
}

__global__ __launch_bounds__(NT) void expand_kernel(
    const float* __restrict__ weight,   // [COUT, CIN, G, 7, 7]
    const float* __restrict__ in_H,     // [8]
    const float* __restrict__ out_H,    // [8]
    const float* __restrict__ grid_Rn,  // [7,7,2]
    const float* __restrict__ mask,     // [7,7]
    float* __restrict__ out)            // [COUT, O, CIN, I, 7, 7]
{
    __shared__ float4 Wl[SLICE];        // [g*49+p] -> {ci0..ci0+3}
    __shared__ float4 wtab[O8 * S49];   // per-(o,s) bilinear weights * mask
    __shared__ unsigned int ttab[O8 * S49]; // per-(o,s) packed tap indices
    __shared__ unsigned int hg[O8 * I8];
    __shared__ float hw[O8 * I8];
    __shared__ __align__(16) float stag[2][RUN]; // double-buffered store staging

    const int tid = threadIdx.x;
    const int bx  = blockIdx.x;
    const int co  = bx >> 5;                 // 32 blocks per co (128 ci / 4)
    const int ci0 = (bx & 31) * CI_PER_BLK;

    // ---- weight staging: transpose 4 ci-slices into float4-interleaved LDS ----
    if (tid < SLICE) {
        const float* b0 = weight + (size_t)(co * CIN + ci0) * SLICE + tid;
        float4 v;
        v.x = b0[0];
        v.y = b0[SLICE];
        v.z = b0[2 * SLICE];
        v.w = b0[3 * SLICE];
        Wl[tid] = v;

        // ---- geometry tables: one thread per (o,s) combo ----
        const int o = tid / S49;
        const int s = tid - o * S49;
        const float gx = grid_Rn[2 * s];
        const float gy = grid_Rn[2 * s + 1];
        const float mv = mask[s];
        const float a  = -out_H[o];          // out_inv, same as reference
        const float c  = cosf(a);
        const float sn = sinf(a);
        const float rx = c * gx - sn * gy;   // left_apply_to_Rn
        const float ry = sn * gx + c * gy;
        const float px = (rx + 1.0f) * 0.5f * (float)(KS - 1);
        const float py = (ry + 1.0f) * 0.5f * (float)(KS - 1);
        const float fx0 = floorf(px), fy0 = floorf(py);
        const float wx = px - fx0, wy = py - fy0;
        const int x0 = (int)fx0, y0 = (int)fy0;
        const int x1 = x0 + 1,   y1 = y0 + 1;
        const int xc0 = min(max(x0, 0), KS - 1);
        const int xc1 = min(max(x1, 0), KS - 1);
        const int yc0 = min(max(y0, 0), KS - 1);
        const int yc1 = min(max(y1, 0), KS - 1);
        const bool ix0 = (x0 >= 0) && (x0 <= KS - 1);
        const bool ix1 = (x1 >= 0) && (x1 <= KS - 1);
        const bool iy0 = (y0 >= 0) && (y0 <= KS - 1);
        const bool iy1 = (y1 >= 0) && (y1 <= KS - 1);
        float w00 = (1.0f - wx) * (1.0f - wy); w00 = (ix0 && iy0) ? w00 : 0.0f;
        float w10 = wx * (1.0f - wy);          w10 = (ix1 && iy0) ? w10 : 0.0f;
        float w01 = (1.0f - wx) * wy;          w01 = (ix0 && iy1) ? w01 : 0.0f;
        float w11 = wx * wy;                   w11 = (ix1 && iy1) ? w11 : 0.0f;
        float4 wv;                            // premultiplied by mask (bf16-absorbed reassoc)
        wv.x = w00 * mv; wv.y = w10 * mv; wv.z = w01 * mv; wv.w = w11 * mv;
        wtab[tid] = wv;
        const unsigned t00 = (unsigned)(yc0 * KS + xc0);
        const unsigned t10 = (unsigned)(yc0 * KS + xc1);
        const unsigned t01 = (unsigned)(yc1 * KS + xc0);
        const unsigned t11 = (unsigned)(yc1 * KS + xc1);
        ttab[tid] = t00 | (t10 << 8) | (t01 << 16) | (t11 << 24);
    }
    if (tid < O8 * I8) {                     // threads 0..63: H-interp table
        const int o = tid >> 3, i = tid & 7;
        const float TP   = 6.28318530717958647692f;   // float32(2*pi)
        const float STEP = 0.78539816339744830961f;   // float32(2*pi/8)
        float q = -out_H[o] + in_H[i];
        float m = fmodf(q, TP);
        if (m < 0.0f) m += TP;               // jnp.mod semantics
        const float pos = m / STEP;
        const float b = floorf(pos);
        const int i0 = ((int)b) & 7;         // b in [0,8], 8&7==0 matches %8
        const int i1 = (i0 + 1) & 7;
        hg[tid] = (unsigned)(i0 * S49) | ((unsigned)(i1 * S49) << 16);
        hw[tid] = pos - b;
    }
    __syncthreads();

    // active threads: tid 0..391 (wave 6 partially active; all 7 waves reach barriers)
    const bool active = (tid < SLICE);
    const int i  = active ? (tid / S49) : 0;          // 0..7
    const int s  = active ? (tid - i * S49) : 0;      // 0..48
    const int sci = tid / (SLICE / CI_PER_BLK);       // store-phase ci (tid/98), 0..3
    const int se4 = tid - sci * (SLICE / CI_PER_BLK); // store-phase float4 idx, 0..97

    // contiguous 1568-float output chunk per (co,o): [co][o][ci0..ci0+3][392]
    size_t ochunk = ((size_t)(co * O8) * CIN + ci0) * SLICE;

    #pragma unroll
    for (int o = 0; o < O8; ++o) {
        float* sb = stag[o & 1];
        if (active) {
            const float4 wv = wtab[o * S49 + s];
            const unsigned tp = ttab[o * S49 + s];
            const int t00 = (int)(tp & 0xffu);
            const int t10 = (int)((tp >> 8) & 0xffu);
            const int t01 = (int)((tp >> 16) & 0xffu);
            const int t11 = (int)(tp >> 24);

            const unsigned hp = hg[(o << 3) + i];
            const float    wh = hw[(o << 3) + i];
            const int g0 = (int)(hp & 0xffffu);
            const int g1 = (int)(hp >> 16);

            float ax, ay, az, aw;
            const bool lo = (wh <= 1e-4f);
            const bool hi = (wh >= 1.0f - 1e-4f);
            if (lo || hi) {
                // degenerate H-blend: single slice; dropped term <= 1e-4*|W| ~ 5e-7
                const int   g  = lo ? g0 : g1;
                const float sc = lo ? (1.0f - wh) : wh;
                const float4 v00 = Wl[g + t00];
                const float4 v10 = Wl[g + t10];
                const float4 v01 = Wl[g + t01];
                const float4 v11 = Wl[g + t11];
                ax = sc * (wv.x * v00.x + wv.y * v10.x + wv.z * v01.x + wv.w * v11.x);
                ay = sc * (wv.x * v00.y + wv.y * v10.y + wv.z * v01.y + wv.w * v11.y);
                az = sc * (wv.x * v00.z + wv.y * v10.z + wv.z * v01.z + wv.w * v11.z);
                aw = sc * (wv.x * v00.w + wv.y * v10.w + wv.z * v01.w + wv.w * v11.w);
            } else {
                const float4 u00 = Wl[g0 + t00];
                const float4 u10 = Wl[g0 + t10];
                const float4 u01 = Wl[g0 + t01];
                const float4 u11 = Wl[g0 + t11];
                const float4 v00 = Wl[g1 + t00];
                const float4 v10 = Wl[g1 + t10];
                const float4 v01 = Wl[g1 + t01];
                const float4 v11 = Wl[g1 + t11];
                const float wA = (1.0f - wh), wB = wh;
                ax = wA * (wv.x * u00.x + wv.y * u10.x + wv.z * u01.x + wv.w * u11.x)
                   + wB * (wv.x * v00.x + wv.y * v10.x + wv.z * v01.x + wv.w * v11.x);
                ay = wA * (wv.x * u00.y + wv.y * u10.y + wv.z * u01.y + wv.w * u11.y)
                   + wB * (wv.x * v00.y + wv.y * v10.y + wv.z * v01.y + wv.w * v11.y);
                az = wA * (wv.x * u00.z + wv.y * u10.z + wv.z * u01.z + wv.w * u11.z)
                   + wB * (wv.x * v00.z + wv.y * v10.z + wv.z * v01.z + wv.w * v11.z);
                aw = wA * (wv.x * u00.w + wv.y * u10.w + wv.z * u01.w + wv.w * u11.w)
                   + wB * (wv.x * v00.w + wv.y * v10.w + wv.z * v01.w + wv.w * v11.w);
            }
            // stage results: [ci][e] layout inside the 1568-float chunk
            sb[            tid] = ax;
            sb[    SLICE + tid] = ay;
            sb[2 * SLICE + tid] = az;
            sb[3 * SLICE + tid] = aw;
        }
        __syncthreads();   // staging visible; also orders o+2 writes after o reads
        if (active) {
            const float4 sv = *reinterpret_cast<const float4*>(&sb[sci * SLICE + 4 * se4]);
            float4* dst = reinterpret_cast<float4*>(out + ochunk + sci * SLICE + 4 * se4);
            *dst = sv;
        }
        ochunk += (size_t)CIN * SLICE;       // advance o by 128*392
    }
}

extern "C" void kernel_launch(void* const* d_in, const int* in_sizes, int n_in,
                              void* d_out, int out_size, void* d_ws, size_t ws_size,
                              hipStream_t stream) {
    const float* weight  = (const float*)d_in[0];
    const float* in_H    = (const float*)d_in[1];
    const float* out_H   = (const float*)d_in[2];
    /* d_in[3] = grid_H (unused) */
    const float* grid_Rn = (const float*)d_in[4];
    const float* mask    = (const float*)d_in[5];
    float* outp = (float*)d_out;

    const int nblocks = COUT * (CIN / CI_PER_BLK);  // 4096
    hipLaunchKernelGGL(expand_kernel, dim3(nblocks), dim3(NT), 0, stream,
                       weight, in_H, out_H, grid_Rn, mask, outp);
}